// Round 10
// baseline (5940.963 us; speedup 1.0000x reference)
//
#include <hip/hip_runtime.h>

// Problem constants
constexpr int B = 64, T = 1024, D = 128, H = 256;
// RNN partition: 16 batch-groups (GB=4) x 16 blocks (16 units each), grid 256.
// Block = 512 threads = 16 units x 32 k-lanes. Weights LDS-stationary (72 KB,
// thread-chunk-sequential float4 layout -> conflict-free lane-stride-16B reads).
constexpr int NG = 16;   // batch groups
constexpr int GB = 4;    // batches per group
constexpr int GK = 16;   // blocks per group
constexpr int UO = 16;   // hidden units owned per block

__device__ __forceinline__ float sigmoidf_(float v) {
    return 1.f / (1.f + __expf(-v));
}
__device__ __forceinline__ float tanhf_(float v) {
    float e2 = __expf(2.f * v);
    return 1.f - 2.f / (e2 + 1.f);
}

// ---------------- P1: per-(b,d) scan over t (prefetch-unrolled) ----------------
__global__ __launch_bounds__(64) void prep_scan(
    const float* __restrict__ x, const int* __restrict__ mask,
    const float* __restrict__ ts, const float* __restrict__ it0,
    float* __restrict__ ffill, float* __restrict__ idelta,
    float* __restrict__ mean, float* __restrict__ tdlv)
{
    const int b = blockIdx.x;
    const int d = blockIdx.y * 64 + threadIdx.x;
    float prev_x = 0.f, prev_td = 0.f, osum = 0.f, mcnt = 0.f;
    float prev_ts = it0[b];               // init_time is (1,B) -> flat[b]
    const int baseT = b * T;
    constexpr int U = 16;
    for (int t0 = 0; t0 < T; t0 += U) {
        float xv[U]; int mv[U]; float tsv[U];
        #pragma unroll
        for (int uu = 0; uu < U; ++uu) {
            const int idx = (baseT + t0 + uu) * D + d;
            xv[uu] = x[idx];
            mv[uu] = mask[idx];
        }
        #pragma unroll
        for (int uu = 0; uu < U; ++uu) tsv[uu] = ts[baseT + t0 + uu];
        #pragma unroll
        for (int uu = 0; uu < U; ++uu) {
            const float td = tsv[uu] - prev_ts;
            prev_ts = tsv[uu];
            const int idx = (baseT + t0 + uu) * D + d;
            if (!mv[uu]) { prev_x = xv[uu]; osum += xv[uu]; } else { mcnt += 1.f; }
            prev_td += td;
            ffill[idx]  = prev_x;
            idelta[idx] = prev_td;
            if (!mv[uu]) prev_td = 0.f;
            if (d == 0) tdlv[baseT + t0 + uu] = logf(fminf(fmaxf(td, 0.f), 1000.f));
        }
    }
    mean[b * D + d] = osum / fmaxf(mcnt, 1.f);
}

// ---------------- P2: imputation matvec ----------------
constexpr int ROWS = 64;   // (b,t) rows per block
__global__ __launch_bounds__(256) void fill_kernel(
    const float* __restrict__ x, const int* __restrict__ mask,
    const float* __restrict__ ffill, const float* __restrict__ idelta,
    const float* __restrict__ mean, const float* __restrict__ idw,
    const float* __restrict__ idb, float* __restrict__ xf)
{
    __shared__ float widw[128 * 129];   // padded: conflict-free
    __shared__ float ide[2][128];
    const int tid = threadIdx.x;
    for (int i = tid; i < 128 * 128; i += 256)
        widw[(i >> 7) * 129 + (i & 127)] = idw[i];
    __syncthreads();
    const int p = tid >> 7, d = tid & 127;
    const float bias = idb[d];
    const int row0 = blockIdx.x * ROWS;
    for (int r = 0; r < ROWS; r += 2) {
        const int rowp = row0 + r + p;    // b*T + t
        const int idx = rowp * D + d;
        ide[p][d] = fminf(fmaxf(idelta[idx] - 1.f, 0.f), 1000.f);
        __syncthreads();
        float acc = bias;
        #pragma unroll
        for (int k = 0; k < 128; ++k)
            acc = fmaf(ide[p][k], widw[d * 129 + k], acc);
        float fw = __expf(-fmaxf(acc, 0.f));
        float filled = ffill[idx] * fw + (1.f - fw) * mean[(rowp >> 10) * D + d];
        xf[idx] = mask[idx] ? filled : x[idx];
        __syncthreads();
    }
}

// ---------------- P3: persistent grouped GRU-D recurrence ----------------
// 16 groups x 16 blocks; block = 16 units x 32 k-lanes, 4 batches, 512 thr.
// Weights LDS-stationary (loaded once, conflict-free chunk layout). Fence-free
// tagged 64-bit LLC exchange (tag = step+1 | f32 bits), parity double-buffered
// hdec (stride-10 chunks), one barrier per step. Reduce-scatter over 32 kc
// lanes (16 items = 4 batches x 4 gate-vals); lanes kc&7==0 publish batch kc>>3.
__global__ __launch_bounds__(512) void rnn_kernel(
    const float* __restrict__ xf, const float* __restrict__ tdlv,
    const float* __restrict__ w_ih, const float* __restrict__ w_hh,
    const float* __restrict__ b_ih, const float* __restrict__ b_hh,
    const float* __restrict__ hdw, const float* __restrict__ hdb,
    unsigned long long* __restrict__ hx, float* __restrict__ out)
{
    const int tid = threadIdx.x;
    const int g  = blockIdx.x & (NG - 1);   // batch group; members bid%16==g -> same XCD
    const int kb = blockIdx.x >> 4;         // 0..15: owns units [kb*16, kb*16+16)
    const int u  = tid >> 5;                // 0..15 unit-local
    const int kc = tid & 31;                // 0..31 k-lane
    const int row = kb * UO + u;            // owned hidden unit
    const int b0 = g * GB;

    // LDS: weights chunk-sequential (chunk c of thread tid at float (c*512+tid)*4)
    // chunks 0..5: w_hh gates r,z,n (2 chunks each = 8 k-floats at kc*8)
    // chunks 6..8: w_ih gates r,z,n (1 chunk each = 4 k-floats at kc*4)
    __shared__ float wlds[9 * 512 * 4];     // 73728 B
    __shared__ float hdec[2 * GB * 320];    // 10240 B  (total 83968 -> 1 block/CU)

    #pragma unroll
    for (int gg = 0; gg < 3; ++gg) {
        #pragma unroll
        for (int jc = 0; jc < 2; ++jc) {
            float4 w = *(const float4*)&w_hh[(size_t)(row + gg * H) * H + kc * 8 + jc * 4];
            *(float4*)&wlds[((gg * 2 + jc) * 512 + tid) * 4] = w;
        }
        float4 wi = *(const float4*)&w_ih[(size_t)(row + gg * H) * D + kc * 4];
        *(float4*)&wlds[((6 + gg) * 512 + tid) * 4] = wi;
    }
    for (int i = tid; i < 2 * GB * 320; i += 512) hdec[i] = 0.f;   // h0 = 0

    // Staging role: thread stages unit sk for batches {sb, sb+2}
    const int sk = tid & 255;
    const int sb = tid >> 8;                // 0..1
    const bool ownk = ((sk >> 4) == kb);    // own-block units are pre-staged
    const float hdwk = hdw[sk], hdbk = hdb[sk];
    const float hdwo = hdw[row], hdbo = hdb[row];
    const bool pub = ((kc & 7) == 0);       // publisher lanes: kc in {0,8,16,24}
    const int pbb = kc >> 3;                // published batch index
    const float br  = b_ih[row] + b_hh[row];
    const float bz  = b_ih[H + row] + b_hh[H + row];
    const float bnx = b_ih[2 * H + row];
    const float bnh = b_hh[2 * H + row];

    __syncthreads();

    for (int t = 0; t < T; ++t) {
        const int par = t & 1;

        // ---- (a) probe the two remote tag words early (hide under gi) ----
        const bool need = (t > 0) && !ownk;
        const unsigned long long* slot0 =
            hx + (size_t)((t - 1) & 1) * (B * H) + (size_t)(b0 + sb) * H + sk;
        const unsigned long long* slot1 = slot0 + 2 * H;   // batch sb+2
        unsigned long long v0 = 0, v1 = 0;
        if (need) {
            v0 = __hip_atomic_load(slot0, __ATOMIC_RELAXED, __HIP_MEMORY_SCOPE_AGENT);
            v1 = __hip_atomic_load(slot1, __ATOMIC_RELAXED, __HIP_MEMORY_SCOPE_AGENT);
        }

        // ---- (b) gi partials: LDS w_ih x global x (independent of h) ----
        float4 wi0 = *(const float4*)&wlds[((6 + 0) * 512 + tid) * 4];
        float4 wi1 = *(const float4*)&wlds[((6 + 1) * 512 + tid) * 4];
        float4 wi2 = *(const float4*)&wlds[((6 + 2) * 512 + tid) * 4];
        float acc[16];
        #pragma unroll
        for (int i = 0; i < 16; ++i) acc[i] = 0.f;
        #pragma unroll
        for (int bb = 0; bb < GB; ++bb) {
            float4 xq = *(const float4*)(xf + (size_t)((b0 + bb) * T + t) * D + kc * 4);
            float a0 = 0.f, a1 = 0.f, a2 = 0.f;
            a0 = fmaf(wi0.x, xq.x, a0); a1 = fmaf(wi1.x, xq.x, a1); a2 = fmaf(wi2.x, xq.x, a2);
            a0 = fmaf(wi0.y, xq.y, a0); a1 = fmaf(wi1.y, xq.y, a1); a2 = fmaf(wi2.y, xq.y, a2);
            a0 = fmaf(wi0.z, xq.z, a0); a1 = fmaf(wi1.z, xq.z, a1); a2 = fmaf(wi2.z, xq.z, a2);
            a0 = fmaf(wi0.w, xq.w, a0); a1 = fmaf(wi1.w, xq.w, a1); a2 = fmaf(wi2.w, xq.w, a2);
            acc[bb * 4 + 0] = a0; acc[bb * 4 + 1] = a1; acc[bb * 4 + 2] = a2;
        }
        float tdn = 0.f;
        if (pub && t + 1 < T) tdn = tdlv[(b0 + pbb) * T + t + 1];

        // hoist gh weight reads (independent of staging)
        float4 whr0 = *(const float4*)&wlds[((0) * 512 + tid) * 4];
        float4 whr1 = *(const float4*)&wlds[((1) * 512 + tid) * 4];
        float4 whz0 = *(const float4*)&wlds[((2) * 512 + tid) * 4];
        float4 whz1 = *(const float4*)&wlds[((3) * 512 + tid) * 4];
        float4 whn0 = *(const float4*)&wlds[((4) * 512 + tid) * 4];
        float4 whn1 = *(const float4*)&wlds[((5) * 512 + tid) * 4];

        // ---- (c) finish poll + stage decayed remote h into LDS ----
        if (need) {
            while (!(((unsigned)(v0 >> 32) == (unsigned)t) &&
                     ((unsigned)(v1 >> 32) == (unsigned)t))) {
                v0 = __hip_atomic_load(slot0, __ATOMIC_RELAXED, __HIP_MEMORY_SCOPE_AGENT);
                v1 = __hip_atomic_load(slot1, __ATOMIC_RELAXED, __HIP_MEMORY_SCOPE_AGENT);
            }
            float td0 = tdlv[(b0 + sb) * T + t];
            float td1 = tdlv[(b0 + sb + 2) * T + t];
            float dec0 = __expf(-fmaxf(td0 * hdwk + hdbk, 0.f));
            float dec1 = __expf(-fmaxf(td1 * hdwk + hdbk, 0.f));
            const int coff = (sk >> 3) * 10 + (sk & 7);
            hdec[par * 1280 + (sb    ) * 320 + coff] = __uint_as_float((unsigned)v0) * dec0;
            hdec[par * 1280 + (sb + 2) * 320 + coff] = __uint_as_float((unsigned)v1) * dec1;
        }
        __syncthreads();

        // ---- (d) gh partials: LDS weights x LDS hdec ----
        #pragma unroll
        for (int bb = 0; bb < GB; ++bb) {
            const float* base = &hdec[par * 1280 + bb * 320 + kc * 10];
            float2 h0 = *(const float2*)(base);
            float2 h1 = *(const float2*)(base + 2);
            float2 h2 = *(const float2*)(base + 4);
            float2 h3 = *(const float2*)(base + 6);
            float a0 = acc[bb * 4 + 0], a1 = acc[bb * 4 + 1], a3 = acc[bb * 4 + 3];
            a0 = fmaf(whr0.x, h0.x, a0); a1 = fmaf(whz0.x, h0.x, a1); a3 = fmaf(whn0.x, h0.x, a3);
            a0 = fmaf(whr0.y, h0.y, a0); a1 = fmaf(whz0.y, h0.y, a1); a3 = fmaf(whn0.y, h0.y, a3);
            a0 = fmaf(whr0.z, h1.x, a0); a1 = fmaf(whz0.z, h1.x, a1); a3 = fmaf(whn0.z, h1.x, a3);
            a0 = fmaf(whr0.w, h1.y, a0); a1 = fmaf(whz0.w, h1.y, a1); a3 = fmaf(whn0.w, h1.y, a3);
            a0 = fmaf(whr1.x, h2.x, a0); a1 = fmaf(whz1.x, h2.x, a1); a3 = fmaf(whn1.x, h2.x, a3);
            a0 = fmaf(whr1.y, h2.y, a0); a1 = fmaf(whz1.y, h2.y, a1); a3 = fmaf(whn1.y, h2.y, a3);
            a0 = fmaf(whr1.z, h3.x, a0); a1 = fmaf(whz1.z, h3.x, a1); a3 = fmaf(whn1.z, h3.x, a3);
            a0 = fmaf(whr1.w, h3.y, a0); a1 = fmaf(whz1.w, h3.y, a1); a3 = fmaf(whn1.w, h3.y, a3);
            acc[bb * 4 + 0] = a0; acc[bb * 4 + 1] = a1; acc[bb * 4 + 3] = a3;
        }

        // ---- (e) reduce-scatter over 32 lanes (16 items); item(kc) = kc>>1 ----
        #pragma unroll
        for (int m = 16; m >= 2; m >>= 1) {
            const bool sel = (kc & m);
            #pragma unroll
            for (int j = 0; j < m / 2; ++j) {
                float lo = acc[j], hi = acc[j + m / 2];
                float keep = sel ? hi : lo;
                float send = sel ? lo : hi;
                acc[j] = keep + __shfl_xor(send, m, 64);
            }
        }
        float vfin = acc[0] + __shfl_xor(acc[0], 1, 64);   // full 32-lane sum
        float zv  = __shfl_xor(vfin, 2, 64);               // item +1 (z)
        float nxv = __shfl_xor(vfin, 4, 64);               // item +2 (nx)
        float nhv = __shfl_xor(vfin, 6, 64);               // item +3 (nh)

        // ---- (f) publisher epilogue (kc in {0,8,16,24}; batch pbb) ----
        if (pub) {
            float hd = hdec[par * 1280 + pbb * 320 + (row >> 3) * 10 + (row & 7)];
            float r = sigmoidf_(vfin + br);
            float z = sigmoidf_(zv + bz);
            float n = tanhf_(nxv + bnx + r * (nhv + bnh));
            float hnew = (1.f - z) * n + z * hd;
            // publish to LLC first (tag = t+1)
            __hip_atomic_store(hx + (size_t)par * (B * H) + (size_t)(b0 + pbb) * H + row,
                               (((unsigned long long)(unsigned)(t + 1)) << 32) |
                               (unsigned long long)__float_as_uint(hnew),
                               __ATOMIC_RELAXED, __HIP_MEMORY_SCOPE_AGENT);
            // pre-stage own unit's decayed h for t+1
            if (t + 1 < T) {
                float dec = __expf(-fmaxf(tdn * hdwo + hdbo, 0.f));
                hdec[(par ^ 1) * 1280 + pbb * 320 + (row >> 3) * 10 + (row & 7)] = hnew * dec;
            }
            out[(size_t)((b0 + pbb) * T + t) * H + row] = hnew;
            if (t == T - 1)
                out[(size_t)B * T * H + (b0 + pbb) * H + row] = hnew;
        }
        // single barrier per step: parity buffering + the collective barrier
        // order all hdec writes before their reads (2-barrier-distance proof).
    }
}

extern "C" void kernel_launch(void* const* d_in, const int* in_sizes, int n_in,
                              void* d_out, int out_size, void* d_ws, size_t ws_size,
                              hipStream_t stream) {
    (void)in_sizes; (void)n_in; (void)out_size; (void)ws_size;
    const float* x    = (const float*)d_in[0];
    const int*   mask = (const int*)d_in[1];
    const float* ts   = (const float*)d_in[2];
    const float* it0  = (const float*)d_in[3];
    const float* w_ih = (const float*)d_in[4];
    const float* w_hh = (const float*)d_in[5];
    const float* b_ih = (const float*)d_in[6];
    const float* b_hh = (const float*)d_in[7];
    const float* idw  = (const float*)d_in[8];
    const float* idb  = (const float*)d_in[9];
    const float* hdw  = (const float*)d_in[10];
    const float* hdb  = (const float*)d_in[11];
    float* out = (float*)d_out;

    // Workspace layout (bytes)
    char* ws = (char*)d_ws;
    float* xf   = (float*)(ws);                              // 33554432 B
    float* tdlv = (float*)(ws + 33554432);                   // 262144 B
    float* mean = (float*)(ws + 33816576);                   // 32768 B
    unsigned long long* hx = (unsigned long long*)(ws + 33849344); // 2*B*H u64

    // d_out used as scratch before the RNN overwrites it entirely:
    float* ffill  = out;
    float* idelta = out + (size_t)B * T * D;

    // zero tag words each launch (replay safety)
    hipMemsetAsync(hx, 0, (size_t)(2 * B * H) * 8, stream);

    prep_scan<<<dim3(B, 2), 64, 0, stream>>>(x, mask, ts, it0, ffill, idelta, mean, tdlv);
    fill_kernel<<<(B * T) / ROWS, 256, 0, stream>>>(x, mask, ffill, idelta, mean, idw, idb, xf);
    rnn_kernel<<<NG * GK, 512, 0, stream>>>(xf, tdlv, w_ih, w_hh, b_ih, b_hh, hdw, hdb,
                                            hx, out);
}

// Round 11
// 2413.907 us; speedup vs baseline: 2.4611x; 2.4611x over previous
//
#include <hip/hip_runtime.h>

// Problem constants
constexpr int B = 64, T = 1024, D = 128, H = 256;
// RNN partition (R4-proven geometry): 64 groups (1 batch each) x 4 blocks of
// 512 threads; 64 units/block, 8 k-lanes/unit. Weights bf16-packed in LDS
// (147 KB, loaded once) -> zero per-step weight traffic from L2.
constexpr int NG = 64;   // groups (= batches)
constexpr int GK = 4;    // blocks per group
constexpr int UO = 64;   // hidden units owned per block
constexpr int CS = 40;   // hdec chunk stride in floats (32 data + 8 skew)

__device__ __forceinline__ float sigmoidf_(float v) {
    return 1.f / (1.f + __expf(-v));
}
__device__ __forceinline__ float tanhf_(float v) {
    float e2 = __expf(2.f * v);
    return 1.f - 2.f / (e2 + 1.f);
}
// round-to-nearest-even bf16 pack of two floats into one u32 (lo16=f0, hi16=f1)
__device__ __forceinline__ unsigned bfpack(float f0, float f1) {
    unsigned a = __float_as_uint(f0), b = __float_as_uint(f1);
    unsigned ra = (a + 0x7fffu + ((a >> 16) & 1u)) >> 16;
    unsigned rb = (b + 0x7fffu + ((b >> 16) & 1u)) >> 16;
    return (ra & 0xffffu) | (rb << 16);
}
__device__ __forceinline__ float blo(unsigned w) { return __uint_as_float(w << 16); }
__device__ __forceinline__ float bhi(unsigned w) { return __uint_as_float(w & 0xffff0000u); }

// acc += dot(8 bf16 weights in W, 8 floats in xa|xb)
#define FMA8(acc, W, xa, xb) do { \
    acc = fmaf(blo(W.x), xa.x, acc); acc = fmaf(bhi(W.x), xa.y, acc); \
    acc = fmaf(blo(W.y), xa.z, acc); acc = fmaf(bhi(W.y), xa.w, acc); \
    acc = fmaf(blo(W.z), xb.x, acc); acc = fmaf(bhi(W.z), xb.y, acc); \
    acc = fmaf(blo(W.w), xb.z, acc); acc = fmaf(bhi(W.w), xb.w, acc); } while (0)

// ---------------- P1: per-(b,d) scan over t (prefetch-unrolled) ----------------
__global__ __launch_bounds__(64) void prep_scan(
    const float* __restrict__ x, const int* __restrict__ mask,
    const float* __restrict__ ts, const float* __restrict__ it0,
    float* __restrict__ ffill, float* __restrict__ idelta,
    float* __restrict__ mean, float* __restrict__ tdlv)
{
    const int b = blockIdx.x;
    const int d = blockIdx.y * 64 + threadIdx.x;
    float prev_x = 0.f, prev_td = 0.f, osum = 0.f, mcnt = 0.f;
    float prev_ts = it0[b];               // init_time is (1,B) -> flat[b]
    const int baseT = b * T;
    constexpr int U = 16;
    for (int t0 = 0; t0 < T; t0 += U) {
        float xv[U]; int mv[U]; float tsv[U];
        #pragma unroll
        for (int uu = 0; uu < U; ++uu) {
            const int idx = (baseT + t0 + uu) * D + d;
            xv[uu] = x[idx];
            mv[uu] = mask[idx];
        }
        #pragma unroll
        for (int uu = 0; uu < U; ++uu) tsv[uu] = ts[baseT + t0 + uu];
        #pragma unroll
        for (int uu = 0; uu < U; ++uu) {
            const float td = tsv[uu] - prev_ts;
            prev_ts = tsv[uu];
            const int idx = (baseT + t0 + uu) * D + d;
            if (!mv[uu]) { prev_x = xv[uu]; osum += xv[uu]; } else { mcnt += 1.f; }
            prev_td += td;
            ffill[idx]  = prev_x;
            idelta[idx] = prev_td;
            if (!mv[uu]) prev_td = 0.f;
            if (d == 0) tdlv[baseT + t0 + uu] = logf(fminf(fmaxf(td, 0.f), 1000.f));
        }
    }
    mean[b * D + d] = osum / fmaxf(mcnt, 1.f);
}

// ---------------- P2: imputation matvec ----------------
constexpr int ROWS = 64;   // (b,t) rows per block
__global__ __launch_bounds__(256) void fill_kernel(
    const float* __restrict__ x, const int* __restrict__ mask,
    const float* __restrict__ ffill, const float* __restrict__ idelta,
    const float* __restrict__ mean, const float* __restrict__ idw,
    const float* __restrict__ idb, float* __restrict__ xf)
{
    __shared__ float widw[128 * 129];   // padded: conflict-free
    __shared__ float ide[2][128];
    const int tid = threadIdx.x;
    for (int i = tid; i < 128 * 128; i += 256)
        widw[(i >> 7) * 129 + (i & 127)] = idw[i];
    __syncthreads();
    const int p = tid >> 7, d = tid & 127;
    const float bias = idb[d];
    const int row0 = blockIdx.x * ROWS;
    for (int r = 0; r < ROWS; r += 2) {
        const int rowp = row0 + r + p;    // b*T + t
        const int idx = rowp * D + d;
        ide[p][d] = fminf(fmaxf(idelta[idx] - 1.f, 0.f), 1000.f);
        __syncthreads();
        float acc = bias;
        #pragma unroll
        for (int k = 0; k < 128; ++k)
            acc = fmaf(ide[p][k], widw[d * 129 + k], acc);
        float fw = __expf(-fmaxf(acc, 0.f));
        float filled = ffill[idx] * fw + (1.f - fw) * mean[(rowp >> 10) * D + d];
        xf[idx] = mask[idx] ? filled : x[idx];
        __syncthreads();
    }
}

// ---------------- P3: persistent grouped GRU-D recurrence ----------------
// R4 exchange structure: 64 one-batch groups x 4 blocks; fence-free tagged
// 64-bit LLC exchange (tag = step+1 | f32 bits), parity double-buffered hdec
// (CS=40, 0 conflicts), one barrier per step, publisher lanes (kc==0)
// pre-stage own units for t+1. NEW: all weights bf16-packed in LDS (147 KB,
// staged once) -> zero per-step weight stream from L2.
__global__ __launch_bounds__(512) void rnn_kernel(
    const float* __restrict__ xf, const float* __restrict__ tdlv,
    const float* __restrict__ w_ih, const float* __restrict__ w_hh,
    const float* __restrict__ b_ih, const float* __restrict__ b_hh,
    const float* __restrict__ hdw, const float* __restrict__ hdb,
    unsigned long long* __restrict__ hx, float* __restrict__ out)
{
    const int tid = threadIdx.x;
    const int g  = blockIdx.x & (NG - 1);   // group = batch (members same XCD mod 8)
    const int kb = blockIdx.x >> 6;         // 0..3: owns units [kb*64, kb*64+64)
    const int u_loc = tid >> 3;             // 0..63
    const int kc = tid & 7;                 // 0..7 k-lane
    const int row = kb * UO + u_loc;        // owned hidden unit
    const int b = g;

    // LDS: bf16 weights, thread-chunk-sequential uint4 layout.
    // gh chunks c = gate*4 + jc (c=0..11): k in [kc*32 + jc*8, +8)
    // gi chunks c = 12 + gate*2 + jc (c=12..17): k in [kc*16 + jc*8, +8)
    // chunk c of thread tid at u32 offset (c*512 + tid)*4  (byte 16*(c*512+tid))
    __shared__ unsigned wlds[18 * 512 * 4];   // 147456 B
    __shared__ float hdec[2][8 * CS];         // 2560 B  (total 150016 B)

    #pragma unroll
    for (int gg = 0; gg < 3; ++gg)
        #pragma unroll
        for (int jc = 0; jc < 4; ++jc) {
            const float* src = &w_hh[(size_t)(row + gg * H) * H + kc * 32 + jc * 8];
            float4 f0 = *(const float4*)src;
            float4 f1 = *(const float4*)(src + 4);
            uint4 p;
            p.x = bfpack(f0.x, f0.y); p.y = bfpack(f0.z, f0.w);
            p.z = bfpack(f1.x, f1.y); p.w = bfpack(f1.z, f1.w);
            *(uint4*)&wlds[((gg * 4 + jc) * 512 + tid) * 4] = p;
        }
    #pragma unroll
    for (int gg = 0; gg < 3; ++gg)
        #pragma unroll
        for (int jc = 0; jc < 2; ++jc) {
            const float* src = &w_ih[(size_t)(row + gg * H) * D + kc * 16 + jc * 8];
            float4 f0 = *(const float4*)src;
            float4 f1 = *(const float4*)(src + 4);
            uint4 p;
            p.x = bfpack(f0.x, f0.y); p.y = bfpack(f0.z, f0.w);
            p.z = bfpack(f1.x, f1.y); p.w = bfpack(f1.z, f1.w);
            *(uint4*)&wlds[((12 + gg * 2 + jc) * 512 + tid) * 4] = p;
        }
    for (int i = tid; i < 2 * 8 * CS; i += 512)
        ((float*)hdec)[i] = 0.f;            // h0 = 0 (decayed 0 is 0)

    // Staging role: threads 0..255 stage unit sk = tid
    const bool stager = (tid < H);
    const bool ownk = stager && ((tid >> 6) == kb);
    const float hdwk = stager ? hdw[tid] : 0.f;
    const float hdbk = stager ? hdb[tid] : 0.f;
    const float hdwo = hdw[row];            // decay params for owned unit
    const float hdbo = hdb[row];
    float br = 0.f, bz = 0.f, bnx = 0.f, bnh = 0.f;
    if (kc == 0) {
        br  = b_ih[row] + b_hh[row];
        bz  = b_ih[H + row] + b_hh[H + row];
        bnx = b_ih[2 * H + row];
        bnh = b_hh[2 * H + row];
    }
    __syncthreads();

    const float* tdlb = tdlv + b * T;

    for (int t = 0; t < T; ++t) {
        const int par = t & 1;

        // ---- (a) probe the remote tag word early (hide under gi) ----
        const bool need = (t > 0) && stager && !ownk;
        const unsigned long long* slot =
            hx + (size_t)((t - 1) & 1) * (B * H) + b * H + tid;
        unsigned long long v = 0;
        if (need)
            v = __hip_atomic_load(slot, __ATOMIC_RELAXED, __HIP_MEMORY_SCOPE_AGENT);

        // ---- (b) gi partials: bf16 LDS weights x fp32 x ----
        const float4* xp4 = (const float4*)(xf + (size_t)(b * T + t) * D + kc * 16);
        float a0 = 0.f, a1 = 0.f, a2 = 0.f, a3 = 0.f;
        #pragma unroll
        for (int jc = 0; jc < 2; ++jc) {
            float4 x0 = xp4[jc * 2], x1 = xp4[jc * 2 + 1];
            uint4 wr = *(const uint4*)&wlds[((12 + 0 * 2 + jc) * 512 + tid) * 4];
            uint4 wz = *(const uint4*)&wlds[((12 + 1 * 2 + jc) * 512 + tid) * 4];
            uint4 wn = *(const uint4*)&wlds[((12 + 2 * 2 + jc) * 512 + tid) * 4];
            FMA8(a0, wr, x0, x1);
            FMA8(a1, wz, x0, x1);
            FMA8(a2, wn, x0, x1);
        }

        // ---- (c) finish poll + stage decayed remote h into LDS ----
        if (need) {
            while ((unsigned)(v >> 32) != (unsigned)t)
                v = __hip_atomic_load(slot, __ATOMIC_RELAXED, __HIP_MEMORY_SCOPE_AGENT);
            float hv = __uint_as_float((unsigned)v);
            float dec = __expf(-fmaxf(tdlb[t] * hdwk + hdbk, 0.f));
            hdec[par][(tid >> 5) * CS + (tid & 31)] = hv * dec;
        }
        __syncthreads();

        // ---- (d) gh partials: bf16 LDS weights x fp32 hdec (0-conflict) ----
        const float* hbase = &hdec[par][kc * CS];
        #pragma unroll
        for (int jc = 0; jc < 4; ++jc) {
            float4 h0 = *(const float4*)(hbase + jc * 8);
            float4 h1 = *(const float4*)(hbase + jc * 8 + 4);
            uint4 wr = *(const uint4*)&wlds[((0 * 4 + jc) * 512 + tid) * 4];
            uint4 wz = *(const uint4*)&wlds[((1 * 4 + jc) * 512 + tid) * 4];
            uint4 wn = *(const uint4*)&wlds[((2 * 4 + jc) * 512 + tid) * 4];
            FMA8(a0, wr, h0, h1);
            FMA8(a1, wz, h0, h1);
            FMA8(a3, wn, h0, h1);
        }

        // ---- (e) butterfly reduce over the 8 k-chunk lanes ----
        #pragma unroll
        for (int m = 1; m < 8; m <<= 1) {
            a0 += __shfl_xor(a0, m, 64);
            a1 += __shfl_xor(a1, m, 64);
            a2 += __shfl_xor(a2, m, 64);
            a3 += __shfl_xor(a3, m, 64);
        }

        // ---- (f) owner-lane epilogue: hnew, publish first, then stores ----
        if (kc == 0) {
            float hd = hdec[par][(row >> 5) * CS + (row & 31)];
            float r = sigmoidf_(a0 + br);
            float z = sigmoidf_(a1 + bz);
            float n = tanhf_(a2 + bnx + r * (a3 + bnh));
            float hnew = (1.f - z) * n + z * hd;
            // publish to LLC (tag = t+1) -- first, so the store leaves now
            __hip_atomic_store(hx + (size_t)par * (B * H) + b * H + row,
                               (((unsigned long long)(unsigned)(t + 1)) << 32) |
                               (unsigned long long)__float_as_uint(hnew),
                               __ATOMIC_RELAXED, __HIP_MEMORY_SCOPE_AGENT);
            // pre-stage own unit's decayed h for step t+1 (readers of
            // hdec[par^1] only run after next step's barrier)
            if (t + 1 < T) {
                float dec = __expf(-fmaxf(tdlb[t + 1] * hdwo + hdbo, 0.f));
                hdec[par ^ 1][(row >> 5) * CS + (row & 31)] = hnew * dec;
            }
            out[(size_t)(b * T + t) * H + row] = hnew;
            if (t == T - 1)
                out[(size_t)B * T * H + b * H + row] = hnew;
        }
        // no end-of-step barrier: parity buffering + next step's barrier
        // order all hdec writes before their reads (R4-proven).
    }
}

extern "C" void kernel_launch(void* const* d_in, const int* in_sizes, int n_in,
                              void* d_out, int out_size, void* d_ws, size_t ws_size,
                              hipStream_t stream) {
    (void)in_sizes; (void)n_in; (void)out_size; (void)ws_size;
    const float* x    = (const float*)d_in[0];
    const int*   mask = (const int*)d_in[1];
    const float* ts   = (const float*)d_in[2];
    const float* it0  = (const float*)d_in[3];
    const float* w_ih = (const float*)d_in[4];
    const float* w_hh = (const float*)d_in[5];
    const float* b_ih = (const float*)d_in[6];
    const float* b_hh = (const float*)d_in[7];
    const float* idw  = (const float*)d_in[8];
    const float* idb  = (const float*)d_in[9];
    const float* hdw  = (const float*)d_in[10];
    const float* hdb  = (const float*)d_in[11];
    float* out = (float*)d_out;

    // Workspace layout (bytes)
    char* ws = (char*)d_ws;
    float* xf   = (float*)(ws);                              // 33554432 B
    float* tdlv = (float*)(ws + 33554432);                   // 262144 B
    float* mean = (float*)(ws + 33816576);                   // 32768 B
    unsigned long long* hx = (unsigned long long*)(ws + 33849344); // 2*B*H u64

    // d_out used as scratch before the RNN overwrites it entirely:
    float* ffill  = out;
    float* idelta = out + (size_t)B * T * D;

    // zero tag words each launch (replay safety)
    hipMemsetAsync(hx, 0, (size_t)(2 * B * H) * 8, stream);

    prep_scan<<<dim3(B, 2), 64, 0, stream>>>(x, mask, ts, it0, ffill, idelta, mean, tdlv);
    fill_kernel<<<(B * T) / ROWS, 256, 0, stream>>>(x, mask, ffill, idelta, mean, idw, idb, xf);
    rnn_kernel<<<NG * GK, 512, 0, stream>>>(xf, tdlv, w_ih, w_hh, b_ih, b_hh, hdw, hdb,
                                            hx, out);
}